// Round 4
// baseline (1787.514 us; speedup 1.0000x reference)
//
#include <hip/hip_runtime.h>
#include <hip/hip_bf16.h>

// VoxelPooler: scatter-add point features into a dense BEV voxel grid.
// geometry [B=4, N=6, D=41, H=16, W=44, 3] f32
// features [B, N, D, H, W, C=64] f32
// out      [B, Z*C=512, X=200, Y=200] f32, index ((b*Z+z)*C+c)*X*Y + x*Y + y

#define GRID_X 200
#define GRID_Y 200
#define GRID_Z 8
#define NCH 64
#define PTS_PER_BATCH (6 * 41 * 16 * 44)   // 173184
#define TOTAL_POINTS (4 * PTS_PER_BATCH)   // 692736
#define OUT_FLOATS (4LL * GRID_Z * NCH * GRID_X * GRID_Y)  // 81,920,000

// Zero-fill d_out with vector stores (graph-capture-safe).
__global__ __launch_bounds__(256) void zero_kernel(float4* __restrict__ out) {
    const long long n4 = OUT_FLOATS / 4;   // 20,480,000
    long long stride = (long long)gridDim.x * blockDim.x;
    for (long long i = blockIdx.x * (long long)blockDim.x + threadIdx.x;
         i < n4; i += stride) {
        out[i] = make_float4(0.f, 0.f, 0.f, 0.f);
    }
}

__global__ __launch_bounds__(256) void voxel_scatter_kernel(
    const float* __restrict__ geom,
    const float* __restrict__ feat,
    const float* __restrict__ vsz,
    const float* __restrict__ vorg,
    float* __restrict__ out) {
    int gid = blockIdx.x * blockDim.x + threadIdx.x;
    int pt = gid >> 6;        // one point per 64-lane wave
    int c  = gid & 63;        // lane = channel
    if (pt >= TOTAL_POINTS) return;

    // All 64 lanes of the wave load the same 3 floats -> L1 broadcast.
    float px = geom[(size_t)pt * 3 + 0];
    float py = geom[(size_t)pt * 3 + 1];
    float pz = geom[(size_t)pt * 3 + 2];

    // Exact IEEE divide + floorf to match the numpy reference at bin edges.
    int vx = (int)floorf((px - vorg[0]) / vsz[0]);
    int vy = (int)floorf((py - vorg[1]) / vsz[1]);
    int vz = (int)floorf((pz - vorg[2]) / vsz[2]);

    if (vx < 0 || vx >= GRID_X || vy < 0 || vy >= GRID_Y ||
        vz < 0 || vz >= GRID_Z) return;   // invalid points contribute nothing

    int b = pt / PTS_PER_BATCH;

    // Coalesced feature read: lanes c=0..63 read contiguous floats (256 B/wave).
    float f = feat[(size_t)pt * NCH + c];

    // out[b][vz][c][vx][vy]
    size_t idx = ((((size_t)b * GRID_Z + vz) * NCH + c) * GRID_X + vx) * GRID_Y + vy;
    atomicAdd(out + idx, f);
}

extern "C" void kernel_launch(void* const* d_in, const int* in_sizes, int n_in,
                              void* d_out, int out_size, void* d_ws, size_t ws_size,
                              hipStream_t stream) {
    const float* geom = (const float*)d_in[0];
    const float* feat = (const float*)d_in[1];
    const float* vsz  = (const float*)d_in[2];
    const float* vorg = (const float*)d_in[3];
    float* out = (float*)d_out;

    // Zero-init output (harness poisons it with 0xAA before every launch).
    zero_kernel<<<2048, 256, 0, stream>>>((float4*)out);

    // 692736 points * 64 channels = 44,335,104 threads; /256 = 173,184 blocks exact.
    const long long total_threads = (long long)TOTAL_POINTS * NCH;
    const int block = 256;
    const int grid = (int)((total_threads + block - 1) / block);
    voxel_scatter_kernel<<<grid, block, 0, stream>>>(geom, feat, vsz, vorg, out);
}

// Round 5
// 621.781 us; speedup vs baseline: 2.8748x; 2.8748x over previous
//
#include <hip/hip_runtime.h>
#include <hip/hip_bf16.h>

// VoxelPooler via bucket sort: random atomic scatter (R4: 1787us, bound by
// random 64B dirty-line writebacks at ~718 GB/s) -> dense tile writes.
// geometry [B=4, N=6, D=41, H=16, W=44, 3] f32
// features [B, N, D, H, W, C=64] f32
// out      [B, Z*C=512, X=200, Y=200] f32

#define GRID_X 200
#define GRID_Y 200
#define GRID_Z 8
#define NCH 64
#define NB 4
#define PTS_PER_BATCH (6 * 41 * 16 * 44)   // 173184
#define TOTAL_POINTS (NB * PTS_PER_BATCH)  // 692736
#define OUT_FLOATS ((long long)NB * GRID_Z * NCH * GRID_X * GRID_Y)  // 81,920,000

#define YT 4            // y tiles per x-row
#define TILE_Y 50       // GRID_Y / YT
#define NBUCKET (NB * GRID_Z * GRID_X * YT)   // 25600
#define LDS_STRIDE 51   // 51%32=19, coprime with 32 -> 2-way banks (free)

// ws layout (ints): cnt[NBUCKET] | starts[NBUCKET+1] | cursor[NBUCKET] | sorted[TOTAL_POINTS]
#define WS_CNT     0
#define WS_STARTS  (NBUCKET)
#define WS_CURSOR  (2 * NBUCKET + 1)
#define WS_SORTED  (3 * NBUCKET + 1)
#define WS_INTS    (3 * NBUCKET + 1 + TOTAL_POINTS)   // 769,537 -> ~3.08 MB

__device__ __forceinline__ bool point_voxel(const float* __restrict__ geom,
                                            const float* __restrict__ vsz,
                                            const float* __restrict__ vorg,
                                            int i, int& vx, int& vy, int& vz) {
    float px = geom[(size_t)i * 3 + 0];
    float py = geom[(size_t)i * 3 + 1];
    float pz = geom[(size_t)i * 3 + 2];
    // Exact IEEE divide + floorf to match the numpy reference at bin edges.
    vx = (int)floorf((px - vorg[0]) / vsz[0]);
    vy = (int)floorf((py - vorg[1]) / vsz[1]);
    vz = (int)floorf((pz - vorg[2]) / vsz[2]);
    return (vx >= 0 && vx < GRID_X && vy >= 0 && vy < GRID_Y &&
            vz >= 0 && vz < GRID_Z);
}

__device__ __forceinline__ int bucket_of(int b, int vz, int vx, int yt) {
    return ((b * GRID_Z + vz) * GRID_X + vx) * YT + yt;
}

__global__ __launch_bounds__(256) void zero_cnt_kernel(int* __restrict__ cnt) {
    int i = blockIdx.x * 256 + threadIdx.x;
    if (i < NBUCKET) cnt[i] = 0;
}

__global__ __launch_bounds__(256) void hist_kernel(
    const float* __restrict__ geom, const float* __restrict__ vsz,
    const float* __restrict__ vorg, int* __restrict__ cnt) {
    int i = blockIdx.x * 256 + threadIdx.x;
    if (i >= TOTAL_POINTS) return;
    int vx, vy, vz;
    if (!point_voxel(geom, vsz, vorg, i, vx, vy, vz)) return;
    int b = i / PTS_PER_BATCH;
    atomicAdd(&cnt[bucket_of(b, vz, vx, vy / TILE_Y)], 1);
}

// One block, 256 threads, each owns 100 contiguous counters.
__global__ __launch_bounds__(256) void scan_kernel(
    const int* __restrict__ cnt, int* __restrict__ starts, int* __restrict__ cursor) {
    __shared__ int partial[256];
    int t = threadIdx.x;
    const int CHUNK = NBUCKET / 256;   // 100
    int base = t * CHUNK;
    int s = 0;
    for (int j = 0; j < CHUNK; ++j) s += cnt[base + j];
    partial[t] = s;
    __syncthreads();
    for (int off = 1; off < 256; off <<= 1) {
        int v = (t >= off) ? partial[t - off] : 0;
        __syncthreads();
        partial[t] += v;
        __syncthreads();
    }
    int run = partial[t] - s;   // exclusive prefix of this chunk
    for (int j = 0; j < CHUNK; ++j) {
        int c = cnt[base + j];
        starts[base + j] = run;
        cursor[base + j] = run;
        run += c;
    }
    if (t == 255) starts[NBUCKET] = run;   // total valid count sentinel
}

__global__ __launch_bounds__(256) void scatter_idx_kernel(
    const float* __restrict__ geom, const float* __restrict__ vsz,
    const float* __restrict__ vorg, int* __restrict__ cursor,
    unsigned* __restrict__ sorted) {
    int i = blockIdx.x * 256 + threadIdx.x;
    if (i >= TOTAL_POINTS) return;
    int vx, vy, vz;
    if (!point_voxel(geom, vsz, vorg, i, vx, vy, vz)) return;
    int b = i / PTS_PER_BATCH;
    int yt = vy / TILE_Y;
    int yl = vy - yt * TILE_Y;
    int pos = atomicAdd(&cursor[bucket_of(b, vz, vx, yt)], 1);
    sorted[pos] = (unsigned)i | ((unsigned)yl << 20);   // i < 2^20, yl < 64
}

// One block per bucket: gather point features (coalesced 256B, lane=channel),
// accumulate in LDS, dense coalesced write-out (covers ALL cells incl. zeros).
__global__ __launch_bounds__(256) void pool_kernel(
    const float* __restrict__ feat, const unsigned* __restrict__ sorted,
    const int* __restrict__ starts, float* __restrict__ out) {
    __shared__ float acc[NCH * LDS_STRIDE];   // 64*51*4 = 13056 B
    int t = threadIdx.x;
    int bid = blockIdx.x;

    for (int j = t; j < NCH * LDS_STRIDE; j += 256) acc[j] = 0.f;
    __syncthreads();

    int s0 = starts[bid];
    int s1 = starts[bid + 1];
    int w = t >> 6;       // wave id 0..3
    int c = t & 63;       // lane = channel

    for (int p = s0 + w; p < s1; p += 4) {
        unsigned pk = (unsigned)__builtin_amdgcn_readfirstlane((int)sorted[p]);
        unsigned idx = pk & 0xFFFFFu;
        unsigned yl = pk >> 20;
        float f = feat[(size_t)idx * NCH + c];           // coalesced 256B/wave
        atomicAdd(&acc[c * LDS_STRIDE + yl], f);         // ds_add_f32, 2-way banks
    }
    __syncthreads();

    // bid = ((b*GZ+z)*GX + x)*YT + yt
    int yt = bid & 3;
    int x = (bid >> 2) % GRID_X;
    int bz = (bid >> 2) / GRID_X;   // b*GRID_Z + z

    int ly = t & 63;
    if (ly < TILE_Y) {
        for (int k = 0; k < 16; ++k) {
            int cc = w + 4 * k;
            size_t o = (((size_t)bz * NCH + cc) * GRID_X + x) * GRID_Y
                       + (size_t)yt * TILE_Y + ly;
            out[o] = acc[cc * LDS_STRIDE + ly];
        }
    }
}

// ---------- fallback path (R4): atomic scatter ----------
__global__ __launch_bounds__(256) void zero_out_kernel(float4* __restrict__ out) {
    const long long n4 = OUT_FLOATS / 4;
    long long stride = (long long)gridDim.x * blockDim.x;
    for (long long i = blockIdx.x * (long long)blockDim.x + threadIdx.x;
         i < n4; i += stride)
        out[i] = make_float4(0.f, 0.f, 0.f, 0.f);
}

__global__ __launch_bounds__(256) void voxel_scatter_kernel(
    const float* __restrict__ geom, const float* __restrict__ feat,
    const float* __restrict__ vsz, const float* __restrict__ vorg,
    float* __restrict__ out) {
    int gid = blockIdx.x * blockDim.x + threadIdx.x;
    int pt = gid >> 6;
    int c = gid & 63;
    if (pt >= TOTAL_POINTS) return;
    int vx, vy, vz;
    if (!point_voxel(geom, vsz, vorg, pt, vx, vy, vz)) return;
    int b = pt / PTS_PER_BATCH;
    float f = feat[(size_t)pt * NCH + c];
    size_t idx = ((((size_t)b * GRID_Z + vz) * NCH + c) * GRID_X + vx) * GRID_Y + vy;
    atomicAdd(out + idx, f);
}

extern "C" void kernel_launch(void* const* d_in, const int* in_sizes, int n_in,
                              void* d_out, int out_size, void* d_ws, size_t ws_size,
                              hipStream_t stream) {
    const float* geom = (const float*)d_in[0];
    const float* feat = (const float*)d_in[1];
    const float* vsz  = (const float*)d_in[2];
    const float* vorg = (const float*)d_in[3];
    float* out = (float*)d_out;

    if (ws_size >= (size_t)WS_INTS * sizeof(int)) {
        int* ws = (int*)d_ws;
        int* cnt = ws + WS_CNT;
        int* starts = ws + WS_STARTS;
        int* cursor = ws + WS_CURSOR;
        unsigned* sorted = (unsigned*)(ws + WS_SORTED);

        zero_cnt_kernel<<<(NBUCKET + 255) / 256, 256, 0, stream>>>(cnt);
        hist_kernel<<<TOTAL_POINTS / 256, 256, 0, stream>>>(geom, vsz, vorg, cnt);
        scan_kernel<<<1, 256, 0, stream>>>(cnt, starts, cursor);
        scatter_idx_kernel<<<TOTAL_POINTS / 256, 256, 0, stream>>>(
            geom, vsz, vorg, cursor, sorted);
        pool_kernel<<<NBUCKET, 256, 0, stream>>>(feat, sorted, starts, out);
    } else {
        // ws too small: R4 atomic-scatter fallback
        zero_out_kernel<<<2048, 256, 0, stream>>>((float4*)out);
        const long long total_threads = (long long)TOTAL_POINTS * NCH;
        voxel_scatter_kernel<<<(int)((total_threads + 255) / 256), 256, 0, stream>>>(
            geom, feat, vsz, vorg, out);
    }
}

// Round 6
// 604.085 us; speedup vs baseline: 2.9590x; 1.0293x over previous
//
#include <hip/hip_runtime.h>
#include <hip/hip_bf16.h>

// VoxelPooler via bucket sort. R4 atomic scatter: 1787us (random 64B
// writebacks). R5 bucket sort: 622us, pool at 2.0 TB/s. R6: 4-point float4
// gather (4x MLP), TILE_Y=100 tiles, float4 epilogue, cached point codes.
// geometry [B=4, N=6, D=41, H=16, W=44, 3] f32
// features [B, N, D, H, W, C=64] f32
// out      [B, Z*C=512, X=200, Y=200] f32

#define GRID_X 200
#define GRID_Y 200
#define GRID_Z 8
#define NCH 64
#define NB 4
#define PTS_PER_BATCH (6 * 41 * 16 * 44)   // 173184
#define TOTAL_POINTS (NB * PTS_PER_BATCH)  // 692736
#define OUT_FLOATS ((long long)NB * GRID_Z * NCH * GRID_X * GRID_Y)  // 81,920,000

#define YT 2             // y tiles per x-row
#define TILE_Y 100       // GRID_Y / YT
#define NBUCKET (NB * GRID_Z * GRID_X * YT)   // 12800
#define LDS_STRIDE 65    // acc[y][c] padded: gather 2-way banks, epilogue ok

// ws layout (ints):
// cnt[NBUCKET] | starts[NBUCKET+1] | cursor[NBUCKET] | sorted[TOTAL_POINTS] | pcode[TOTAL_POINTS]
#define WS_CNT     0
#define WS_STARTS  (NBUCKET)
#define WS_CURSOR  (2 * NBUCKET + 1)
#define WS_SORTED  (3 * NBUCKET + 1)
#define WS_PCODE   (3 * NBUCKET + 1 + TOTAL_POINTS)
#define WS_INTS    (3 * NBUCKET + 1 + 2 * TOTAL_POINTS)   // ~5.7 MB

__device__ __forceinline__ bool point_voxel(const float* __restrict__ geom,
                                            const float* __restrict__ vsz,
                                            const float* __restrict__ vorg,
                                            int i, int& vx, int& vy, int& vz) {
    float px = geom[(size_t)i * 3 + 0];
    float py = geom[(size_t)i * 3 + 1];
    float pz = geom[(size_t)i * 3 + 2];
    // Exact IEEE divide + floorf to match the numpy reference at bin edges.
    vx = (int)floorf((px - vorg[0]) / vsz[0]);
    vy = (int)floorf((py - vorg[1]) / vsz[1]);
    vz = (int)floorf((pz - vorg[2]) / vsz[2]);
    return (vx >= 0 && vx < GRID_X && vy >= 0 && vy < GRID_Y &&
            vz >= 0 && vz < GRID_Z);
}

__global__ __launch_bounds__(256) void zero_cnt_kernel(int* __restrict__ cnt) {
    int i = blockIdx.x * 256 + threadIdx.x;
    if (i < NBUCKET) cnt[i] = 0;
}

// Histogram + cache packed (bucket, y_local) per point so scatter_idx skips
// the geometry re-read. pcode: bit31=valid, bits[20:14]=yl, bits[13:0]=bucket.
__global__ __launch_bounds__(256) void hist_kernel(
    const float* __restrict__ geom, const float* __restrict__ vsz,
    const float* __restrict__ vorg, int* __restrict__ cnt,
    unsigned* __restrict__ pcode) {
    int i = blockIdx.x * 256 + threadIdx.x;
    if (i >= TOTAL_POINTS) return;
    int vx, vy, vz;
    unsigned code = 0;
    if (point_voxel(geom, vsz, vorg, i, vx, vy, vz)) {
        int b = i / PTS_PER_BATCH;
        int yt = vy / TILE_Y;
        int yl = vy - yt * TILE_Y;
        int bucket = ((b * GRID_Z + vz) * GRID_X + vx) * YT + yt;
        code = 0x80000000u | ((unsigned)yl << 14) | (unsigned)bucket;
        atomicAdd(&cnt[bucket], 1);
    }
    pcode[i] = code;
}

// One block, 256 threads, each owns 50 contiguous counters.
__global__ __launch_bounds__(256) void scan_kernel(
    const int* __restrict__ cnt, int* __restrict__ starts, int* __restrict__ cursor) {
    __shared__ int partial[256];
    int t = threadIdx.x;
    const int CHUNK = NBUCKET / 256;   // 50
    int base = t * CHUNK;
    int s = 0;
    for (int j = 0; j < CHUNK; ++j) s += cnt[base + j];
    partial[t] = s;
    __syncthreads();
    for (int off = 1; off < 256; off <<= 1) {
        int v = (t >= off) ? partial[t - off] : 0;
        __syncthreads();
        partial[t] += v;
        __syncthreads();
    }
    int run = partial[t] - s;   // exclusive prefix of this chunk
    for (int j = 0; j < CHUNK; ++j) {
        int c = cnt[base + j];
        starts[base + j] = run;
        cursor[base + j] = run;
        run += c;
    }
    if (t == 255) starts[NBUCKET] = run;
}

__global__ __launch_bounds__(256) void scatter_idx_kernel(
    const unsigned* __restrict__ pcode, int* __restrict__ cursor,
    unsigned* __restrict__ sorted) {
    int i = blockIdx.x * 256 + threadIdx.x;
    if (i >= TOTAL_POINTS) return;
    unsigned code = pcode[i];
    if (!(code & 0x80000000u)) return;
    int bucket = (int)(code & 0x3FFFu);
    unsigned yl = (code >> 14) & 0x7Fu;
    int pos = atomicAdd(&cursor[bucket], 1);
    sorted[pos] = (unsigned)i | (yl << 20);   // i < 2^20, yl < 128
}

// One block per bucket (b, z, x, yt). Gather: 4 points per wave-iteration,
// 16 lanes x float4 each (1 KB / wave load instr -> 4x MLP vs R5).
// Accumulate acc[y][c] in LDS, dense float4 write-out (covers zeros too).
__global__ __launch_bounds__(256) void pool_kernel(
    const float4* __restrict__ feat4, const unsigned* __restrict__ sorted,
    const int* __restrict__ starts, float4* __restrict__ out4) {
    __shared__ __align__(16) float acc[TILE_Y * LDS_STRIDE];   // 26000 B
    int t = threadIdx.x;
    int bid = blockIdx.x;

    // zero LDS with float4 stores: 6500 floats = 1625 float4
    float4* a4 = (float4*)acc;
    for (int i = t; i < TILE_Y * LDS_STRIDE / 4; i += 256)
        a4[i] = make_float4(0.f, 0.f, 0.f, 0.f);
    __syncthreads();

    int s0 = starts[bid];
    int s1 = starts[bid + 1];
    int w = t >> 6;            // wave 0..3
    int g = (t >> 4) & 3;      // point slot within wave
    int l = t & 15;            // float4 slot: channels 4l..4l+3

    for (int p0 = s0 + w * 4; p0 < s1; p0 += 16) {
        int p = p0 + g;
        if (p < s1) {
            unsigned pk = sorted[p];
            unsigned idx = pk & 0xFFFFFu;
            unsigned yl = pk >> 20;
            float4 f = feat4[(size_t)idx * 16 + l];
            float* row = &acc[yl * LDS_STRIDE + 4 * l];
            atomicAdd(row + 0, f.x);
            atomicAdd(row + 1, f.y);
            atomicAdd(row + 2, f.z);
            atomicAdd(row + 3, f.w);
        }
    }
    __syncthreads();

    // bid = ((b*GZ+z)*GX + x)*YT + yt
    int yt = bid & 1;
    int x = (bid >> 1) % GRID_X;
    int bz = (bid >> 1) / GRID_X;   // b*GRID_Z + z

    // 64 channels x 25 float4 (=100 y) = 1600 float4 stores, coalesced.
    for (int i = t; i < NCH * (TILE_Y / 4); i += 256) {
        int cc = i / (TILE_Y / 4);
        int j = i % (TILE_Y / 4);
        int y0 = 4 * j;
        float4 v = make_float4(acc[(y0 + 0) * LDS_STRIDE + cc],
                               acc[(y0 + 1) * LDS_STRIDE + cc],
                               acc[(y0 + 2) * LDS_STRIDE + cc],
                               acc[(y0 + 3) * LDS_STRIDE + cc]);
        // float index: (((bz*64+cc)*200 + x)*200 + yt*100 + 4j), /4 below
        size_t o4 = (((size_t)bz * NCH + cc) * GRID_X + x) * (GRID_Y / 4)
                    + yt * (TILE_Y / 4) + j;
        out4[o4] = v;
    }
}

// ---------- fallback path (R4): atomic scatter ----------
__global__ __launch_bounds__(256) void zero_out_kernel(float4* __restrict__ out) {
    const long long n4 = OUT_FLOATS / 4;
    long long stride = (long long)gridDim.x * blockDim.x;
    for (long long i = blockIdx.x * (long long)blockDim.x + threadIdx.x;
         i < n4; i += stride)
        out[i] = make_float4(0.f, 0.f, 0.f, 0.f);
}

__global__ __launch_bounds__(256) void voxel_scatter_kernel(
    const float* __restrict__ geom, const float* __restrict__ feat,
    const float* __restrict__ vsz, const float* __restrict__ vorg,
    float* __restrict__ out) {
    int gid = blockIdx.x * blockDim.x + threadIdx.x;
    int pt = gid >> 6;
    int c = gid & 63;
    if (pt >= TOTAL_POINTS) return;
    int vx, vy, vz;
    if (!point_voxel(geom, vsz, vorg, pt, vx, vy, vz)) return;
    int b = pt / PTS_PER_BATCH;
    float f = feat[(size_t)pt * NCH + c];
    size_t idx = ((((size_t)b * GRID_Z + vz) * NCH + c) * GRID_X + vx) * GRID_Y + vy;
    atomicAdd(out + idx, f);
}

extern "C" void kernel_launch(void* const* d_in, const int* in_sizes, int n_in,
                              void* d_out, int out_size, void* d_ws, size_t ws_size,
                              hipStream_t stream) {
    const float* geom = (const float*)d_in[0];
    const float* feat = (const float*)d_in[1];
    const float* vsz  = (const float*)d_in[2];
    const float* vorg = (const float*)d_in[3];
    float* out = (float*)d_out;

    if (ws_size >= (size_t)WS_INTS * sizeof(int)) {
        int* ws = (int*)d_ws;
        int* cnt = ws + WS_CNT;
        int* starts = ws + WS_STARTS;
        int* cursor = ws + WS_CURSOR;
        unsigned* sorted = (unsigned*)(ws + WS_SORTED);
        unsigned* pcode  = (unsigned*)(ws + WS_PCODE);

        zero_cnt_kernel<<<(NBUCKET + 255) / 256, 256, 0, stream>>>(cnt);
        hist_kernel<<<TOTAL_POINTS / 256, 256, 0, stream>>>(geom, vsz, vorg, cnt, pcode);
        scan_kernel<<<1, 256, 0, stream>>>(cnt, starts, cursor);
        scatter_idx_kernel<<<TOTAL_POINTS / 256, 256, 0, stream>>>(pcode, cursor, sorted);
        pool_kernel<<<NBUCKET, 256, 0, stream>>>(
            (const float4*)feat, sorted, starts, (float4*)out);
    } else {
        // ws too small: R4 atomic-scatter fallback
        zero_out_kernel<<<2048, 256, 0, stream>>>((float4*)out);
        const long long total_threads = (long long)TOTAL_POINTS * NCH;
        voxel_scatter_kernel<<<(int)((total_threads + 255) / 256), 256, 0, stream>>>(
            geom, feat, vsz, vorg, out);
    }
}